// Round 6
// baseline (296.854 us; speedup 1.0000x reference)
//
#include <hip/hip_runtime.h>

#define T_SEQ 2048
#define DMODEL 2048
#define NHEADS 16
#define NKV 4
#define HDIM 128
#define KVDIM (NKV*HDIM)          // 512
#define QKVN (DMODEL + 2*KVDIM)   // 3072

typedef __bf16 bf16x8 __attribute__((ext_vector_type(8)));
typedef float f32x4 __attribute__((ext_vector_type(4)));
typedef unsigned short us8 __attribute__((ext_vector_type(8)));
typedef unsigned short ushort_t;

__device__ __forceinline__ ushort_t f2b(float f) {
    union { float f; unsigned u; } c; c.f = f;
    unsigned r = c.u + 0x7FFFu + ((c.u >> 16) & 1u);
    return (ushort_t)(r >> 16);
}
__device__ __forceinline__ ushort_t f2b_rn(float f) {   // native cvt (RTNE), hot path
    union { __bf16 h; ushort_t u; } c; c.h = (__bf16)f; return c.u;
}
__device__ __forceinline__ float b2f(ushort_t b) {
    union { unsigned u; float f; } c; c.u = ((unsigned)b) << 16; return c.f;
}

#define GLDS(g, l) __builtin_amdgcn_global_load_lds( \
    (const __attribute__((address_space(1))) void*)(g), \
    (__attribute__((address_space(3))) void*)(l), 16, 0, 0)

// ---------------------------------------------------------------- convert (all 5 tensors, 1 launch)
__global__ __launch_bounds__(256) void cvt5_kernel(
    const float* __restrict__ s0, ushort_t* __restrict__ d0, int c0,
    const float* __restrict__ s1, ushort_t* __restrict__ d1, int c1,
    const float* __restrict__ s2, ushort_t* __restrict__ d2, int c2,
    const float* __restrict__ s3, ushort_t* __restrict__ d3, int c3,
    const float* __restrict__ s4, ushort_t* __restrict__ d4, int c4)
{
    int u = blockIdx.x * 256 + threadIdx.x;   // float4 index
    const float* s; ushort_t* d; int off;
    if      (u < c0) { s = s0; d = d0; off = u; }
    else if (u < c1) { s = s1; d = d1; off = u - c0; }
    else if (u < c2) { s = s2; d = d2; off = u - c1; }
    else if (u < c3) { s = s3; d = d3; off = u - c2; }
    else if (u < c4) { s = s4; d = d4; off = u - c3; }
    else return;
    const float4 v = *(const float4*)(s + off * 4);
    ushort4 o = make_ushort4(f2b(v.x), f2b(v.y), f2b(v.z), f2b(v.w));
    *(ushort4*)(d + off * 4) = o;
}

// ---------------------------------------------------------------- GEMM C = A @ B^T
// A: M x K bf16 row-major, B: N x K bf16 row-major. 128x128 tile, BK=64,
// 256 threads = 4 waves (2x2), each wave 64x64 (4x4 frags of 16x16x32 MFMA).
// MODE 1: f32 out. MODE 2: bf16 out, V-columns (n0 >= 2560) transposed to VT.
template<int MODE>
__global__ __launch_bounds__(256) void gemm_bt(
    const ushort_t* __restrict__ A, const ushort_t* __restrict__ B,
    ushort_t* __restrict__ Cb, float* __restrict__ Cf, ushort_t* __restrict__ VT,
    int M, int N, int K)
{
    __shared__ ushort_t As[128 * 64];
    __shared__ ushort_t Bs[128 * 64];
    const int tid = threadIdx.x;
    const int lane = tid & 63;
    const int wv = tid >> 6;
    const int wr = wv >> 1, wc = wv & 1;
    const int lrow = lane & 15, lhi = lane >> 4;
    const int m0 = blockIdx.y * 128, n0 = blockIdx.x * 128;

    f32x4 acc[4][4];
#pragma unroll
    for (int i = 0; i < 4; i++)
#pragma unroll
        for (int j = 0; j < 4; j++) acc[i][j] = f32x4{0.f, 0.f, 0.f, 0.f};

    const int srow = tid >> 3;          // 0..31
    const int scol = (tid & 7) * 8;     // 0..56

    for (int kt = 0; kt < K; kt += 64) {
        if (kt) __syncthreads();
#pragma unroll
        for (int r = 0; r < 4; ++r) {
            int row = srow + r * 32;
            GLDS(A + (size_t)(m0 + row) * K + kt + scol, As + row * 64 + scol);
            GLDS(B + (size_t)(n0 + row) * K + kt + scol, Bs + row * 64 + scol);
        }
        __syncthreads();
#pragma unroll
        for (int kk = 0; kk < 2; ++kk) {
            bf16x8 af[4], bfr[4];
#pragma unroll
            for (int i = 0; i < 4; i++)
                af[i] = *(const bf16x8*)(As + (wr * 64 + i * 16 + lrow) * 64 + kk * 32 + lhi * 8);
#pragma unroll
            for (int j = 0; j < 4; j++)
                bfr[j] = *(const bf16x8*)(Bs + (wc * 64 + j * 16 + lrow) * 64 + kk * 32 + lhi * 8);
#pragma unroll
            for (int i = 0; i < 4; i++)
#pragma unroll
                for (int j = 0; j < 4; j++)
                    acc[i][j] = __builtin_amdgcn_mfma_f32_16x16x32_bf16(af[i], bfr[j], acc[i][j], 0, 0, 0);
        }
    }
    if (MODE == 2 && n0 >= DMODEL + KVDIM) {
        // V block: write transposed VT[col][row], 4 consecutive rows pack to 8B
#pragma unroll
        for (int i = 0; i < 4; i++)
#pragma unroll
            for (int j = 0; j < 4; j++) {
                int col = n0 + wc * 64 + j * 16 + lrow - (DMODEL + KVDIM);
                int row0 = m0 + wr * 64 + i * 16 + lhi * 4;
                ushort4 pk = make_ushort4(f2b(acc[i][j][0]), f2b(acc[i][j][1]),
                                          f2b(acc[i][j][2]), f2b(acc[i][j][3]));
                *(ushort4*)(VT + (size_t)col * T_SEQ + row0) = pk;
            }
    } else {
#pragma unroll
        for (int i = 0; i < 4; i++)
#pragma unroll
            for (int j = 0; j < 4; j++)
#pragma unroll
                for (int e = 0; e < 4; e++) {
                    int row = m0 + wr * 64 + i * 16 + lhi * 4 + e;
                    int col = n0 + wc * 64 + j * 16 + lrow;
                    if (MODE == 1) Cf[(size_t)row * N + col] = acc[i][j][e];
                    else           Cb[(size_t)row * N + col] = f2b(acc[i][j][e]);
                }
    }
}

// ---------------------------------------------------------------- RMSNorm + RoPE (Q and K in one launch)
template<int DROW>
__device__ __forceinline__ void norm_rope_body(
    const ushort_t* __restrict__ src, int sld, int scol,
    const float* __restrict__ w,
    const float* __restrict__ cosT, const float* __restrict__ sinT,
    ushort_t* __restrict__ dst, int dld, float oscale,
    float* rowbuf, float* red)
{
    constexpr int PER = DROW / 256;
    const int tid = threadIdx.x;
    const int t = blockIdx.x;
    const ushort_t* rp = src + (size_t)t * sld + scol;
    const int e0 = tid * PER;

    float vals[PER];
    if constexpr (PER == 8) {
        us8 u = *(const us8*)(rp + e0);
#pragma unroll
        for (int p = 0; p < PER; p++) vals[p] = b2f(u[p]);
    } else {
        ushort2 u = *(const ushort2*)(rp + e0);
        vals[0] = b2f(u.x); vals[1] = b2f(u.y);
    }
    float ss = 0.f;
#pragma unroll
    for (int p = 0; p < PER; p++) { ss += vals[p] * vals[p]; rowbuf[e0 + p] = vals[p]; }
#pragma unroll
    for (int o = 32; o; o >>= 1) ss += __shfl_down(ss, o);
    if ((tid & 63) == 0) red[tid >> 6] = ss;
    __syncthreads();
    float rn = rsqrtf((red[0] + red[1] + red[2] + red[3]) / (float)DROW + 1e-6f);
#pragma unroll
    for (int p = 0; p < PER; p++) {
        int e = e0 + p, r = e & 127;
        float c = cosT[t * HDIM + r], s = sinT[t * HDIM + r];
        int pe = (r < 64) ? e + 64 : e - 64;
        float self = rowbuf[e] * rn * w[e];
        float part = rowbuf[pe] * rn * w[pe];
        float o = (r < 64) ? (self * c - part * s) : (self * c + part * s);
        dst[(size_t)t * dld + e] = f2b(o * oscale);
    }
}

__global__ __launch_bounds__(256) void norm_rope_qk(
    const ushort_t* __restrict__ qkv,
    const float* __restrict__ qw, const float* __restrict__ kw,
    const float* __restrict__ cosT, const float* __restrict__ sinT,
    ushort_t* __restrict__ qb, ushort_t* __restrict__ kb)
{
    __shared__ float rowbuf[DMODEL];
    __shared__ float red[4];
    if (blockIdx.y == 0)
        norm_rope_body<DMODEL>(qkv, QKVN, 0, qw, cosT, sinT, qb, DMODEL,
                               0.08838834764831843f, rowbuf, red);
    else
        norm_rope_body<KVDIM>(qkv, QKVN, DMODEL, kw, cosT, sinT, kb, KVDIM,
                              1.0f, rowbuf, red);
}

// ---------------------------------------------------------------- flash attention
// grid (NHEADS, 64). qt = 63 - blockIdx.y (LPT). 128 threads = 2 waves;
// wave w owns q-rows [qt*32 + w*16, +16). KVBLK=32. LDS 34 KB -> 4 blocks/CU.
// SWAPPED QK^T: sf = mfma(K, Q) so lane (lane&15) owns ONE q-row with its
// keys in-register -> softmax is in-lane + 2 shfl_xor. Both-sides XOR swizzle.
__global__ __launch_bounds__(128, 2) void fattn(
    const ushort_t* __restrict__ Q,   // (T, 2048) bf16 normed+roped+scaled
    const ushort_t* __restrict__ Kb,  // (T, 512) bf16 normed+roped
    const ushort_t* __restrict__ VT,  // (512, T) bf16  (V transposed)
    ushort_t* __restrict__ ctx)       // (T, 2048) bf16
{
    __shared__ ushort_t Ks[2][32 * 128];
    __shared__ ushort_t Vt[2][128 * 32];
    __shared__ ushort_t Pw[2][16 * 32];
    const int tid = threadIdx.x, lane = tid & 63, wv = tid >> 6;
    const int lrow = lane & 15, lhi = lane >> 4;
    const int h = blockIdx.x;
    const int qt = 63 - (int)blockIdx.y;
    const int g = h >> 2;
    const int q0 = qt * 32;
    const int sw = (lrow >> 1) & 3;     // V/P unit swizzle
    const int kswz = lrow & 7;          // K unit swizzle

    const int srK = tid >> 4, scK = tid & 15;  // K tile: 16 units/row
    const int srV = tid >> 2, scV = tid & 3;   // VT tile: 4 units/row

    bf16x8 qf[4];
    {
        int qr = q0 + wv * 16 + lrow;
#pragma unroll
        for (int ks = 0; ks < 4; ks++)
            qf[ks] = *(const bf16x8*)(Q + (size_t)qr * DMODEL + h * HDIM + ks * 32 + lhi * 8);
    }
    f32x4 of[8];
#pragma unroll
    for (int f = 0; f < 8; f++) of[f] = f32x4{0.f, 0.f, 0.f, 0.f};
    float m_ = -1e30f, l_ = 0.f;        // scalar: lane owns q-row q0+wv*16+lrow
    const int myq = q0 + wv * 16 + lrow;

    auto stage = [&](int kt, int b) {
        const int k0 = kt * 32;
#pragma unroll
        for (int r = 0; r < 4; r++) {
            int row = r * 8 + srK;
            GLDS(Kb + (size_t)(k0 + row) * KVDIM + g * HDIM + ((scK ^ (row & 7)) << 3),
                 Ks[b] + row * 128 + (scK << 3));
        }
#pragma unroll
        for (int r = 0; r < 4; r++) {
            int row = r * 32 + srV;
            GLDS(VT + (size_t)(g * HDIM + row) * T_SEQ + k0 + ((scV ^ ((row >> 1) & 3)) << 3),
                 Vt[b] + row * 32 + (scV << 3));
        }
    };

    stage(0, 0);
    __syncthreads();
    int buf = 0;

    for (int kt = 0; kt <= qt; ++kt) {
        if (kt < qt) stage(kt + 1, buf ^ 1);
        const ushort_t* KsB = Ks[buf];
        const ushort_t* VtB = Vt[buf];
        const int k0 = kt * 32;

        // swapped QK^T: sf[nf][j] = S[q = myq][key = k0 + nf*16 + lhi*4 + j]
        f32x4 sf[2];
        sf[0] = f32x4{0.f, 0.f, 0.f, 0.f};
        sf[1] = f32x4{0.f, 0.f, 0.f, 0.f};
#pragma unroll
        for (int ks = 0; ks < 4; ks++) {
#pragma unroll
            for (int nf = 0; nf < 2; nf++) {
                bf16x8 kf = *(const bf16x8*)(KsB + (nf * 16 + lrow) * 128 +
                                             (((ks * 4 + lhi) ^ kswz) << 3));
                sf[nf] = __builtin_amdgcn_mfma_f32_16x16x32_bf16(kf, qf[ks], sf[nf], 0, 0, 0);
            }
        }
        // causal mask (all in-lane)
#pragma unroll
        for (int nf = 0; nf < 2; nf++)
#pragma unroll
            for (int j = 0; j < 4; j++)
                if (k0 + nf * 16 + lhi * 4 + j > myq) sf[nf][j] = -1e30f;
        // row max: in-lane over 8, then across the 4 lhi-mates (2 shfl)
        float mx = fmaxf(fmaxf(fmaxf(sf[0][0], sf[0][1]), fmaxf(sf[0][2], sf[0][3])),
                         fmaxf(fmaxf(sf[1][0], sf[1][1]), fmaxf(sf[1][2], sf[1][3])));
        mx = fmaxf(mx, __shfl_xor(mx, 16));
        mx = fmaxf(mx, __shfl_xor(mx, 32));
        // defer-max (T13)
        if (!__all(mx - m_ <= 8.0f)) {
            float mn = fmaxf(m_, mx);
            float sc = __expf(m_ - mn);
            m_ = mn;
            l_ *= sc;
            float scb[4];
#pragma unroll
            for (int j = 0; j < 4; j++) scb[j] = __shfl(sc, lhi * 4 + j);
#pragma unroll
            for (int f = 0; f < 8; f++)
#pragma unroll
                for (int j = 0; j < 4; j++) of[f][j] *= scb[j];
        }
        // P = exp(S - m), per-lane partial l
        float pf[2][4];
#pragma unroll
        for (int nf = 0; nf < 2; nf++)
#pragma unroll
            for (int j = 0; j < 4; j++) {
                pf[nf][j] = __expf(sf[nf][j] - m_);
                l_ += pf[nf][j];
            }
        // P -> LDS: row q=lrow, 4 contiguous keys per write (2x ds_write_b64)
#pragma unroll
        for (int nf = 0; nf < 2; nf++) {
            ushort4 pk = make_ushort4(f2b_rn(pf[nf][0]), f2b_rn(pf[nf][1]),
                                      f2b_rn(pf[nf][2]), f2b_rn(pf[nf][3]));
            int u = 2 * nf + (lhi >> 1);
            *(ushort4*)(Pw[wv] + lrow * 32 + ((u ^ sw) << 3) + ((lhi & 1) << 2)) = pk;
        }
        // PV: of[f] += P[16x32] @ V^T[d-rows]   (C row = q = lhi*4+j, col = d)
        bf16x8 pa = *(const bf16x8*)(Pw[wv] + lrow * 32 + ((lhi ^ sw) << 3));
#pragma unroll
        for (int f = 0; f < 8; f++) {
            bf16x8 vf = *(const bf16x8*)(VtB + (f * 16 + lrow) * 32 + ((lhi ^ sw) << 3));
            of[f] = __builtin_amdgcn_mfma_f32_16x16x32_bf16(pa, vf, of[f], 0, 0, 0);
        }
        __syncthreads();   // next tile staged + all waves done with buf
        buf ^= 1;
    }
    // final l: reduce across lhi-mates, broadcast to output layout q=lhi*4+j
    l_ += __shfl_xor(l_, 16);
    l_ += __shfl_xor(l_, 32);
    float lb[4];
#pragma unroll
    for (int j = 0; j < 4; j++) lb[j] = __shfl(l_, lhi * 4 + j);
#pragma unroll
    for (int f = 0; f < 8; f++)
#pragma unroll
        for (int j = 0; j < 4; j++) {
            int qrow = q0 + wv * 16 + lhi * 4 + j;
            ctx[(size_t)qrow * DMODEL + h * HDIM + f * 16 + lrow] = f2b_rn(of[f][j] / lb[j]);
        }
}

// ---------------------------------------------------------------- launch
extern "C" void kernel_launch(void* const* d_in, const int* in_sizes, int n_in,
                              void* d_out, int out_size, void* d_ws, size_t ws_size,
                              hipStream_t stream)
{
    const float* x    = (const float*)d_in[0];
    const float* cosT = (const float*)d_in[2];
    const float* sinT = (const float*)d_in[3];
    const float* Wq   = (const float*)d_in[4];
    const float* Wk   = (const float*)d_in[5];
    const float* Wv   = (const float*)d_in[6];
    const float* Wo   = (const float*)d_in[7];
    const float* qw   = (const float*)d_in[8];
    const float* kw   = (const float*)d_in[9];
    float* out = (float*)d_out;

    char* ws = (char*)d_ws;
    size_t off = 0;
    auto alloc = [&](size_t bytes) -> char* {
        char* p = ws + off; off += (bytes + 255) & ~(size_t)255; return p;
    };
    ushort_t* xb    = (ushort_t*)alloc((size_t)T_SEQ * DMODEL * 2);
    ushort_t* wqkvb = (ushort_t*)alloc((size_t)QKVN * DMODEL * 2);
    ushort_t* wob   = (ushort_t*)alloc((size_t)DMODEL * DMODEL * 2);
    ushort_t* qkvb  = (ushort_t*)alloc((size_t)T_SEQ * QKVN * 2);
    ushort_t* qb    = (ushort_t*)alloc((size_t)T_SEQ * DMODEL * 2);
    ushort_t* kb    = (ushort_t*)alloc((size_t)T_SEQ * KVDIM * 2);
    ushort_t* ctxb  = (ushort_t*)alloc((size_t)T_SEQ * DMODEL * 2);
    ushort_t* vtb   = (ushort_t*)alloc((size_t)KVDIM * T_SEQ * 2);

    // one cvt launch for all five tensors (float4 units, cumulative bounds)
    const int n_x  = T_SEQ * DMODEL / 4;
    const int n_wq = DMODEL * DMODEL / 4;
    const int n_wk = KVDIM * DMODEL / 4;
    const int n_wv = KVDIM * DMODEL / 4;
    const int n_wo = DMODEL * DMODEL / 4;
    const int c0 = n_x, c1 = c0 + n_wq, c2 = c1 + n_wk, c3 = c2 + n_wv, c4 = c3 + n_wo;
    cvt5_kernel<<<dim3((c4 + 255) / 256), dim3(256), 0, stream>>>(
        x,  xb, c0,
        Wq, wqkvb, c1,
        Wk, wqkvb + (size_t)DMODEL * DMODEL, c2,
        Wv, wqkvb + (size_t)(DMODEL + KVDIM) * DMODEL, c3,
        Wo, wob, c4);

    gemm_bt<2><<<dim3(QKVN / 128, T_SEQ / 128), dim3(256), 0, stream>>>(
        xb, wqkvb, qkvb, nullptr, vtb, T_SEQ, QKVN, DMODEL);

    norm_rope_qk<<<dim3(T_SEQ, 2), dim3(256), 0, stream>>>(
        qkvb, qw, kw, cosT, sinT, qb, kb);

    fattn<<<dim3(NHEADS, 64), dim3(128), 0, stream>>>(qb, kb, vtb, ctxb);

    gemm_bt<1><<<dim3(DMODEL / 128, T_SEQ / 128), dim3(256), 0, stream>>>(
        ctxb, wob, nullptr, out, nullptr, T_SEQ, DMODEL, DMODEL);
}

// Round 9
// 296.199 us; speedup vs baseline: 1.0022x; 1.0022x over previous
//
#include <hip/hip_runtime.h>

#define T_SEQ 2048
#define DMODEL 2048
#define NHEADS 16
#define NKV 4
#define HDIM 128
#define KVDIM (NKV*HDIM)          // 512
#define QKVN (DMODEL + 2*KVDIM)   // 3072

typedef __bf16 bf16x8 __attribute__((ext_vector_type(8)));
typedef float f32x4 __attribute__((ext_vector_type(4)));
typedef unsigned short us8 __attribute__((ext_vector_type(8)));
typedef unsigned short ushort_t;

__device__ __forceinline__ ushort_t f2b(float f) {
    union { float f; unsigned u; } c; c.f = f;
    unsigned r = c.u + 0x7FFFu + ((c.u >> 16) & 1u);
    return (ushort_t)(r >> 16);
}
__device__ __forceinline__ ushort_t f2b_rn(float f) {   // native cvt (RTNE), hot path
    union { __bf16 h; ushort_t u; } c; c.h = (__bf16)f; return c.u;
}
__device__ __forceinline__ float b2f(ushort_t b) {
    union { unsigned u; float f; } c; c.u = ((unsigned)b) << 16; return c.f;
}

#define GLDS(g, l) __builtin_amdgcn_global_load_lds( \
    (const __attribute__((address_space(1))) void*)(g), \
    (__attribute__((address_space(3))) void*)(l), 16, 0, 0)

// ---------------------------------------------------------------- convert (all 5 tensors, 1 launch)
__global__ __launch_bounds__(256) void cvt5_kernel(
    const float* __restrict__ s0, ushort_t* __restrict__ d0, int c0,
    const float* __restrict__ s1, ushort_t* __restrict__ d1, int c1,
    const float* __restrict__ s2, ushort_t* __restrict__ d2, int c2,
    const float* __restrict__ s3, ushort_t* __restrict__ d3, int c3,
    const float* __restrict__ s4, ushort_t* __restrict__ d4, int c4)
{
    int u = blockIdx.x * 256 + threadIdx.x;   // float4 index
    const float* s; ushort_t* d; int off;
    if      (u < c0) { s = s0; d = d0; off = u; }
    else if (u < c1) { s = s1; d = d1; off = u - c0; }
    else if (u < c2) { s = s2; d = d2; off = u - c1; }
    else if (u < c3) { s = s3; d = d3; off = u - c2; }
    else if (u < c4) { s = s4; d = d4; off = u - c3; }
    else return;
    const float4 v = *(const float4*)(s + off * 4);
    ushort4 o = make_ushort4(f2b(v.x), f2b(v.y), f2b(v.z), f2b(v.w));
    *(ushort4*)(d + off * 4) = o;
}

// ---------------------------------------------------------------- GEMM C = A @ B^T
// A: M x K bf16 row-major, B: N x K bf16 row-major. 128x128 tile, BK=64,
// 256 threads = 4 waves (2x2), each wave 64x64 (4x4 frags of 16x16x32 MFMA).
// MODE 1: f32 out. MODE 2: bf16 out, V-columns (n0 >= 2560) transposed to VT.
template<int MODE>
__global__ __launch_bounds__(256) void gemm_bt(
    const ushort_t* __restrict__ A, const ushort_t* __restrict__ B,
    ushort_t* __restrict__ Cb, float* __restrict__ Cf, ushort_t* __restrict__ VT,
    int M, int N, int K)
{
    __shared__ ushort_t As[128 * 64];
    __shared__ ushort_t Bs[128 * 64];
    const int tid = threadIdx.x;
    const int lane = tid & 63;
    const int wv = tid >> 6;
    const int wr = wv >> 1, wc = wv & 1;
    const int lrow = lane & 15, lhi = lane >> 4;
    const int m0 = blockIdx.y * 128, n0 = blockIdx.x * 128;

    f32x4 acc[4][4];
#pragma unroll
    for (int i = 0; i < 4; i++)
#pragma unroll
        for (int j = 0; j < 4; j++) acc[i][j] = f32x4{0.f, 0.f, 0.f, 0.f};

    const int srow = tid >> 3;          // 0..31
    const int scol = (tid & 7) * 8;     // 0..56

    for (int kt = 0; kt < K; kt += 64) {
        if (kt) __syncthreads();
#pragma unroll
        for (int r = 0; r < 4; ++r) {
            int row = srow + r * 32;
            GLDS(A + (size_t)(m0 + row) * K + kt + scol, As + row * 64 + scol);
            GLDS(B + (size_t)(n0 + row) * K + kt + scol, Bs + row * 64 + scol);
        }
        __syncthreads();
#pragma unroll
        for (int kk = 0; kk < 2; ++kk) {
            bf16x8 af[4], bfr[4];
#pragma unroll
            for (int i = 0; i < 4; i++)
                af[i] = *(const bf16x8*)(As + (wr * 64 + i * 16 + lrow) * 64 + kk * 32 + lhi * 8);
#pragma unroll
            for (int j = 0; j < 4; j++)
                bfr[j] = *(const bf16x8*)(Bs + (wc * 64 + j * 16 + lrow) * 64 + kk * 32 + lhi * 8);
#pragma unroll
            for (int i = 0; i < 4; i++)
#pragma unroll
                for (int j = 0; j < 4; j++)
                    acc[i][j] = __builtin_amdgcn_mfma_f32_16x16x32_bf16(af[i], bfr[j], acc[i][j], 0, 0, 0);
        }
    }
    if (MODE == 2 && n0 >= DMODEL + KVDIM) {
        // V block: write transposed VT[col][row], 4 consecutive rows pack to 8B
#pragma unroll
        for (int i = 0; i < 4; i++)
#pragma unroll
            for (int j = 0; j < 4; j++) {
                int col = n0 + wc * 64 + j * 16 + lrow - (DMODEL + KVDIM);
                int row0 = m0 + wr * 64 + i * 16 + lhi * 4;
                ushort4 pk = make_ushort4(f2b(acc[i][j][0]), f2b(acc[i][j][1]),
                                          f2b(acc[i][j][2]), f2b(acc[i][j][3]));
                *(ushort4*)(VT + (size_t)col * T_SEQ + row0) = pk;
            }
    } else {
#pragma unroll
        for (int i = 0; i < 4; i++)
#pragma unroll
            for (int j = 0; j < 4; j++)
#pragma unroll
                for (int e = 0; e < 4; e++) {
                    int row = m0 + wr * 64 + i * 16 + lhi * 4 + e;
                    int col = n0 + wc * 64 + j * 16 + lrow;
                    if (MODE == 1) Cf[(size_t)row * N + col] = acc[i][j][e];
                    else           Cb[(size_t)row * N + col] = f2b(acc[i][j][e]);
                }
    }
}

// ---------------------------------------------------------------- RMSNorm + RoPE (Q and K in one launch)
template<int DROW>
__device__ __forceinline__ void norm_rope_body(
    const ushort_t* __restrict__ src, int sld, int scol,
    const float* __restrict__ w,
    const float* __restrict__ cosT, const float* __restrict__ sinT,
    ushort_t* __restrict__ dst, int dld, float oscale,
    float* rowbuf, float* red)
{
    constexpr int PER = DROW / 256;
    const int tid = threadIdx.x;
    const int t = blockIdx.x;
    const ushort_t* rp = src + (size_t)t * sld + scol;
    const int e0 = tid * PER;

    float vals[PER];
    if constexpr (PER == 8) {
        us8 u = *(const us8*)(rp + e0);
#pragma unroll
        for (int p = 0; p < PER; p++) vals[p] = b2f(u[p]);
    } else {
        ushort2 u = *(const ushort2*)(rp + e0);
        vals[0] = b2f(u.x); vals[1] = b2f(u.y);
    }
    float ss = 0.f;
#pragma unroll
    for (int p = 0; p < PER; p++) { ss += vals[p] * vals[p]; rowbuf[e0 + p] = vals[p]; }
#pragma unroll
    for (int o = 32; o; o >>= 1) ss += __shfl_down(ss, o);
    if ((tid & 63) == 0) red[tid >> 6] = ss;
    __syncthreads();
    float rn = rsqrtf((red[0] + red[1] + red[2] + red[3]) / (float)DROW + 1e-6f);
#pragma unroll
    for (int p = 0; p < PER; p++) {
        int e = e0 + p, r = e & 127;
        float c = cosT[t * HDIM + r], s = sinT[t * HDIM + r];
        int pe = (r < 64) ? e + 64 : e - 64;
        float self = rowbuf[e] * rn * w[e];
        float part = rowbuf[pe] * rn * w[pe];
        float o = (r < 64) ? (self * c - part * s) : (self * c + part * s);
        dst[(size_t)t * dld + e] = f2b(o * oscale);
    }
}

__global__ __launch_bounds__(256) void norm_rope_qk(
    const ushort_t* __restrict__ qkv,
    const float* __restrict__ qw, const float* __restrict__ kw,
    const float* __restrict__ cosT, const float* __restrict__ sinT,
    ushort_t* __restrict__ qb, ushort_t* __restrict__ kb)
{
    __shared__ float rowbuf[DMODEL];
    __shared__ float red[4];
    if (blockIdx.y == 0)
        norm_rope_body<DMODEL>(qkv, QKVN, 0, qw, cosT, sinT, qb, DMODEL,
                               0.08838834764831843f, rowbuf, red);
    else
        norm_rope_body<KVDIM>(qkv, QKVN, DMODEL, kw, cosT, sinT, kb, KVDIM,
                              1.0f, rowbuf, red);
}

// ---------------------------------------------------------------- flash attention
// grid (NHEADS, 64). qt = 63 - blockIdx.y (LPT). 128 threads = 2 waves;
// wave w owns q-rows [qt*32 + w*16, +16). KVBLK=32. Swapped QK^T (lane owns
// one q-row). TRIPLE-buffered, depth-2 prefetch, COUNTED vmcnt + raw
// s_barrier (T4): compute(t) -> stage(t+2) -> vmcnt(8) [waits only t+1,
// issued a full iter ago; t+2 stays in flight] -> s_barrier. No vmcnt(0)
// drain in steady state. Each wave issues 8 GLDS per stage (4 K + 4 V).
__global__ __launch_bounds__(128) void fattn(
    const ushort_t* __restrict__ Q,   // (T, 2048) bf16 normed+roped+scaled
    const ushort_t* __restrict__ Kb,  // (T, 512) bf16 normed+roped
    const ushort_t* __restrict__ VT,  // (512, T) bf16  (V transposed)
    ushort_t* __restrict__ ctx)       // (T, 2048) bf16
{
    __shared__ ushort_t Ks[3][32 * 128];   // 24 KB
    __shared__ ushort_t Vt[3][128 * 32];   // 24 KB
    __shared__ ushort_t Pw[2][16 * 32];    // 2 KB  (per-wave P)
    const int tid = threadIdx.x, lane = tid & 63, wv = tid >> 6;
    const int lrow = lane & 15, lhi = lane >> 4;
    const int h = blockIdx.x;
    const int qt = 63 - (int)blockIdx.y;
    const int g = h >> 2;
    const int q0 = qt * 32;
    const int sw = (lrow >> 1) & 3;     // V/P unit swizzle
    const int kswz = lrow & 7;          // K unit swizzle

    const int srK = tid >> 4, scK = tid & 15;  // K tile: 16 units/row
    const int srV = tid >> 2, scV = tid & 3;   // VT tile: 4 units/row

    bf16x8 qf[4];
    {
        int qr = q0 + wv * 16 + lrow;
#pragma unroll
        for (int ks = 0; ks < 4; ks++)
            qf[ks] = *(const bf16x8*)(Q + (size_t)qr * DMODEL + h * HDIM + ks * 32 + lhi * 8);
    }
    f32x4 of[8];
#pragma unroll
    for (int f = 0; f < 8; f++) of[f] = f32x4{0.f, 0.f, 0.f, 0.f};
    float m_ = -1e30f, l_ = 0.f;        // scalar: lane owns q-row q0+wv*16+lrow
    const int myq = q0 + wv * 16 + lrow;

    auto stage = [&](int kt, int b) {
        const int k0 = kt * 32;
#pragma unroll
        for (int r = 0; r < 4; r++) {
            int row = r * 8 + srK;
            GLDS(Kb + (size_t)(k0 + row) * KVDIM + g * HDIM + ((scK ^ (row & 7)) << 3),
                 Ks[b] + row * 128 + (scK << 3));
        }
#pragma unroll
        for (int r = 0; r < 4; r++) {
            int row = r * 32 + srV;
            GLDS(VT + (size_t)(g * HDIM + row) * T_SEQ + k0 + ((scV ^ ((row >> 1) & 3)) << 3),
                 Vt[b] + row * 32 + (scV << 3));
        }
    };

    // prologue: stage tiles 0 and 1; wait only for tile 0 (+qf) to land
    stage(0, 0);
    if (qt >= 1) {
        stage(1, 1);
        asm volatile("s_waitcnt vmcnt(8)" ::: "memory");
    } else {
        asm volatile("s_waitcnt vmcnt(0)" ::: "memory");
    }
    __builtin_amdgcn_s_barrier();
    __builtin_amdgcn_sched_barrier(0);

    for (int kt = 0; kt <= qt; ++kt) {
        const int b = kt - (kt / 3) * 3;          // kt % 3
        const ushort_t* KsB = Ks[b];
        const ushort_t* VtB = Vt[b];
        const int k0 = kt * 32;

        // swapped QK^T: sf[nf][j] = S[q = myq][key = k0 + nf*16 + lhi*4 + j]
        f32x4 sf[2];
        sf[0] = f32x4{0.f, 0.f, 0.f, 0.f};
        sf[1] = f32x4{0.f, 0.f, 0.f, 0.f};
#pragma unroll
        for (int ks = 0; ks < 4; ks++) {
#pragma unroll
            for (int nf = 0; nf < 2; nf++) {
                bf16x8 kf = *(const bf16x8*)(KsB + (nf * 16 + lrow) * 128 +
                                             (((ks * 4 + lhi) ^ kswz) << 3));
                sf[nf] = __builtin_amdgcn_mfma_f32_16x16x32_bf16(kf, qf[ks], sf[nf], 0, 0, 0);
            }
        }
        // causal mask (all in-lane)
#pragma unroll
        for (int nf = 0; nf < 2; nf++)
#pragma unroll
            for (int j = 0; j < 4; j++)
                if (k0 + nf * 16 + lhi * 4 + j > myq) sf[nf][j] = -1e30f;
        // row max: in-lane over 8, then across the 4 lhi-mates (2 shfl)
        float mx = fmaxf(fmaxf(fmaxf(sf[0][0], sf[0][1]), fmaxf(sf[0][2], sf[0][3])),
                         fmaxf(fmaxf(sf[1][0], sf[1][1]), fmaxf(sf[1][2], sf[1][3])));
        mx = fmaxf(mx, __shfl_xor(mx, 16));
        mx = fmaxf(mx, __shfl_xor(mx, 32));
        // defer-max (T13)
        if (!__all(mx - m_ <= 8.0f)) {
            float mn = fmaxf(m_, mx);
            float sc = __expf(m_ - mn);
            m_ = mn;
            l_ *= sc;
            float scb[4];
#pragma unroll
            for (int j = 0; j < 4; j++) scb[j] = __shfl(sc, lhi * 4 + j);
#pragma unroll
            for (int f = 0; f < 8; f++)
#pragma unroll
                for (int j = 0; j < 4; j++) of[f][j] *= scb[j];
        }
        // P = exp(S - m), per-lane partial l
        float pf[2][4];
#pragma unroll
        for (int nf = 0; nf < 2; nf++)
#pragma unroll
            for (int j = 0; j < 4; j++) {
                pf[nf][j] = __expf(sf[nf][j] - m_);
                l_ += pf[nf][j];
            }
        // P -> LDS: row q=lrow, 4 contiguous keys per write (2x ds_write_b64)
#pragma unroll
        for (int nf = 0; nf < 2; nf++) {
            ushort4 pk = make_ushort4(f2b_rn(pf[nf][0]), f2b_rn(pf[nf][1]),
                                      f2b_rn(pf[nf][2]), f2b_rn(pf[nf][3]));
            int u = 2 * nf + (lhi >> 1);
            *(ushort4*)(Pw[wv] + lrow * 32 + ((u ^ sw) << 3) + ((lhi & 1) << 2)) = pk;
        }
        // PV: of[f] += P[16x32] @ V^T[d-rows]   (C row = q = lhi*4+j, col = d)
        bf16x8 pa = *(const bf16x8*)(Pw[wv] + lrow * 32 + ((lhi ^ sw) << 3));
#pragma unroll
        for (int f = 0; f < 8; f++) {
            bf16x8 vf = *(const bf16x8*)(VtB + (f * 16 + lrow) * 32 + ((lhi ^ sw) << 3));
            of[f] = __builtin_amdgcn_mfma_f32_16x16x32_bf16(pa, vf, of[f], 0, 0, 0);
        }

        const int rem = qt - kt;
        if (rem == 0) break;               // last tile: no wait/barrier needed
        if (rem >= 2) {
            stage(kt + 2, (kt + 2) - ((kt + 2) / 3) * 3);
            asm volatile("s_waitcnt vmcnt(8)" ::: "memory");   // t+1 landed, t+2 in flight
        } else {
            asm volatile("s_waitcnt vmcnt(0)" ::: "memory");   // tail: only t+1 outstanding
        }
        __builtin_amdgcn_s_barrier();
        __builtin_amdgcn_sched_barrier(0);
    }
    // final l: reduce across lhi-mates, broadcast to output layout q=lhi*4+j
    l_ += __shfl_xor(l_, 16);
    l_ += __shfl_xor(l_, 32);
    float lb[4];
#pragma unroll
    for (int j = 0; j < 4; j++) lb[j] = __shfl(l_, lhi * 4 + j);
#pragma unroll
    for (int f = 0; f < 8; f++)
#pragma unroll
        for (int j = 0; j < 4; j++) {
            int qrow = q0 + wv * 16 + lhi * 4 + j;
            ctx[(size_t)qrow * DMODEL + h * HDIM + f * 16 + lrow] = f2b_rn(of[f][j] / lb[j]);
        }
}

// ---------------------------------------------------------------- launch
extern "C" void kernel_launch(void* const* d_in, const int* in_sizes, int n_in,
                              void* d_out, int out_size, void* d_ws, size_t ws_size,
                              hipStream_t stream)
{
    const float* x    = (const float*)d_in[0];
    const float* cosT = (const float*)d_in[2];
    const float* sinT = (const float*)d_in[3];
    const float* Wq   = (const float*)d_in[4];
    const float* Wk   = (const float*)d_in[5];
    const float* Wv   = (const float*)d_in[6];
    const float* Wo   = (const float*)d_in[7];
    const float* qw   = (const float*)d_in[8];
    const float* kw   = (const float*)d_in[9];
    float* out = (float*)d_out;

    char* ws = (char*)d_ws;
    size_t off = 0;
    auto alloc = [&](size_t bytes) -> char* {
        char* p = ws + off; off += (bytes + 255) & ~(size_t)255; return p;
    };
    ushort_t* xb    = (ushort_t*)alloc((size_t)T_SEQ * DMODEL * 2);
    ushort_t* wqkvb = (ushort_t*)alloc((size_t)QKVN * DMODEL * 2);
    ushort_t* wob   = (ushort_t*)alloc((size_t)DMODEL * DMODEL * 2);
    ushort_t* qkvb  = (ushort_t*)alloc((size_t)T_SEQ * QKVN * 2);
    ushort_t* qb    = (ushort_t*)alloc((size_t)T_SEQ * DMODEL * 2);
    ushort_t* kb    = (ushort_t*)alloc((size_t)T_SEQ * KVDIM * 2);
    ushort_t* ctxb  = (ushort_t*)alloc((size_t)T_SEQ * DMODEL * 2);
    ushort_t* vtb   = (ushort_t*)alloc((size_t)KVDIM * T_SEQ * 2);

    // one cvt launch for all five tensors (float4 units, cumulative bounds)
    const int n_x  = T_SEQ * DMODEL / 4;
    const int n_wq = DMODEL * DMODEL / 4;
    const int n_wk = KVDIM * DMODEL / 4;
    const int n_wv = KVDIM * DMODEL / 4;
    const int n_wo = DMODEL * DMODEL / 4;
    const int c0 = n_x, c1 = c0 + n_wq, c2 = c1 + n_wk, c3 = c2 + n_wv, c4 = c3 + n_wo;
    cvt5_kernel<<<dim3((c4 + 255) / 256), dim3(256), 0, stream>>>(
        x,  xb, c0,
        Wq, wqkvb, c1,
        Wk, wqkvb + (size_t)DMODEL * DMODEL, c2,
        Wv, wqkvb + (size_t)(DMODEL + KVDIM) * DMODEL, c3,
        Wo, wob, c4);

    gemm_bt<2><<<dim3(QKVN / 128, T_SEQ / 128), dim3(256), 0, stream>>>(
        xb, wqkvb, qkvb, nullptr, vtb, T_SEQ, QKVN, DMODEL);

    norm_rope_qk<<<dim3(T_SEQ, 2), dim3(256), 0, stream>>>(
        qkvb, qw, kw, cosT, sinT, qb, kb);

    fattn<<<dim3(NHEADS, 64), dim3(128), 0, stream>>>(qb, kb, vtb, ctxb);

    gemm_bt<1><<<dim3(DMODEL / 128, T_SEQ / 128), dim3(256), 0, stream>>>(
        ctxb, wob, nullptr, out, nullptr, T_SEQ, DMODEL, DMODEL);
}